// Round 1
// baseline (1705.477 us; speedup 1.0000x reference)
//
#include <hip/hip_runtime.h>

#define D 64

// ---------------------------------------------------------------------------
// Edge scatter: 16 threads per edge, 4 features each (float4 gather of x[src],
// 4 hardware fp32 atomic adds into nsum[dst]). Lane 0 of each 16-group also
// counts the in-degree.
// ---------------------------------------------------------------------------
__global__ __launch_bounds__(256) void edge_scatter(
    const float* __restrict__ x,
    const int* __restrict__ src,
    const int* __restrict__ dst,
    float* __restrict__ nsum,
    float* __restrict__ deg,
    int n_edges)
{
    int t = blockIdx.x * blockDim.x + threadIdx.x;
    int e = t >> 4;
    if (e >= n_edges) return;
    int sub = t & 15;

    int s = src[e];
    int d = dst[e];

    const float4 v = *reinterpret_cast<const float4*>(x + (size_t)s * D + sub * 4);
    float* base = nsum + (size_t)d * D + sub * 4;
    unsafeAtomicAdd(base + 0, v.x);
    unsafeAtomicAdd(base + 1, v.y);
    unsafeAtomicAdd(base + 2, v.z);
    unsafeAtomicAdd(base + 3, v.w);

    if (sub == 0) unsafeAtomicAdd(deg + d, 1.0f);
}

// ---------------------------------------------------------------------------
// Node phase: one wave per node. h = (nsum[n] + x[n]) / (deg[n]+1), then
// out[n][o] = sum_k h[k] * W[o][k] + b[o].  W staged transposed in LDS so the
// per-k read Wt[k*64 + lane] is lane-consecutive (bank-conflict-free); h[k]
// broadcast via __shfl.
// ---------------------------------------------------------------------------
__global__ __launch_bounds__(256) void node_gemv(
    const float* __restrict__ x,
    const float* __restrict__ nsum,
    const float* __restrict__ deg,
    const float* __restrict__ W,
    const float* __restrict__ b,
    float* __restrict__ out,
    int n_nodes)
{
    __shared__ float Wt[D * D];  // Wt[k*64 + o] = W[o*64 + k]
    for (int idx = threadIdx.x; idx < D * D; idx += blockDim.x) {
        int o = idx >> 6;
        int k = idx & 63;
        Wt[k * D + o] = W[idx];
    }
    __syncthreads();

    const int wave = threadIdx.x >> 6;   // 0..3
    const int lane = threadIdx.x & 63;
    const float bias = b[lane];
    const int wavesTotal = gridDim.x * 4;

    for (int n = blockIdx.x * 4 + wave; n < n_nodes; n += wavesTotal) {
        const size_t row = (size_t)n * D;
        float dv = deg[n];
        float rinv = 1.0f / (dv + 1.0f);
        float h = (nsum[row + lane] + x[row + lane]) * rinv;

        float acc = 0.0f;
#pragma unroll
        for (int k = 0; k < D; ++k) {
            float hk = __shfl(h, k, 64);
            acc = fmaf(hk, Wt[k * D + lane], acc);
        }
        out[row + lane] = acc + bias;
    }
}

extern "C" void kernel_launch(void* const* d_in, const int* in_sizes, int n_in,
                              void* d_out, int out_size, void* d_ws, size_t ws_size,
                              hipStream_t stream)
{
    const float* x   = (const float*)d_in[0];
    const int*   src = (const int*)d_in[1];
    const int*   dst = (const int*)d_in[2];
    const float* W   = (const float*)d_in[3];
    const float* b   = (const float*)d_in[4];
    float* out = (float*)d_out;

    const int n_nodes = in_sizes[0] / D;
    const int n_edges = in_sizes[1];

    float* nsum = (float*)d_ws;                       // n_nodes * 64 floats
    float* deg  = nsum + (size_t)n_nodes * D;         // n_nodes floats

    size_t zero_bytes = ((size_t)n_nodes * D + n_nodes) * sizeof(float);
    hipMemsetAsync(d_ws, 0, zero_bytes, stream);

    // Edge scatter: 16 threads per edge.
    {
        long long threads = (long long)n_edges * 16;
        int block = 256;
        int grid = (int)((threads + block - 1) / block);
        edge_scatter<<<grid, block, 0, stream>>>(x, src, dst, nsum, deg, n_edges);
    }

    // Node GEMV: one wave per node, 4 waves per block.
    {
        int block = 256;
        int grid = (n_nodes + 3) / 4;
        node_gemv<<<grid, block, 0, stream>>>(x, nsum, deg, W, b, out, n_nodes);
    }
}

// Round 2
// 545.543 us; speedup vs baseline: 3.1262x; 3.1262x over previous
//
#include <hip/hip_runtime.h>

#define D 64
#define SCAN_BLOCK 256

// ---------------------------------------------------------------------------
// 1. Count in-degrees: deg[dst[e]]++ (int atomics, 1.6M total).
// ---------------------------------------------------------------------------
__global__ __launch_bounds__(256) void k_count(
    const int* __restrict__ dst, int* __restrict__ deg, int n_edges)
{
    int t = blockIdx.x * blockDim.x + threadIdx.x;
    if (t < n_edges) atomicAdd(&deg[dst[t]], 1);
}

// ---------------------------------------------------------------------------
// 2a. Block-wise exclusive scan of deg -> offs; per-block totals -> bsum.
// ---------------------------------------------------------------------------
__global__ __launch_bounds__(SCAN_BLOCK) void k_scan1(
    const int* __restrict__ deg, int* __restrict__ offs,
    int* __restrict__ bsum, int n)
{
    __shared__ int s[SCAN_BLOCK];
    int tid = threadIdx.x;
    int i = blockIdx.x * SCAN_BLOCK + tid;
    int v = (i < n) ? deg[i] : 0;
    s[tid] = v;
    __syncthreads();
    for (int off = 1; off < SCAN_BLOCK; off <<= 1) {
        int t = (tid >= off) ? s[tid - off] : 0;
        __syncthreads();
        s[tid] += t;
        __syncthreads();
    }
    if (i < n) offs[i] = s[tid] - v;                 // exclusive
    if (tid == SCAN_BLOCK - 1) bsum[blockIdx.x] = s[tid];
}

// ---------------------------------------------------------------------------
// 2b. Scan the (<=512) block sums in one block; also write offs[n] = total.
// ---------------------------------------------------------------------------
__global__ __launch_bounds__(512) void k_scan2(
    int* __restrict__ bsum, int* __restrict__ offs, int nb, int n)
{
    __shared__ int s[512];
    int tid = threadIdx.x;
    int v = (tid < nb) ? bsum[tid] : 0;
    s[tid] = v;
    __syncthreads();
    for (int off = 1; off < 512; off <<= 1) {
        int t = (tid >= off) ? s[tid - off] : 0;
        __syncthreads();
        s[tid] += t;
        __syncthreads();
    }
    if (tid < nb) bsum[tid] = s[tid] - v;            // exclusive
    if (tid == 511) offs[n] = s[511];                // grand total = n_edges
}

// ---------------------------------------------------------------------------
// 2c. Add scanned block sums back.
// ---------------------------------------------------------------------------
__global__ __launch_bounds__(SCAN_BLOCK) void k_scan3(
    int* __restrict__ offs, const int* __restrict__ bsum, int n)
{
    int i = blockIdx.x * SCAN_BLOCK + threadIdx.x;
    if (i < n) offs[i] += bsum[blockIdx.x];
}

// ---------------------------------------------------------------------------
// 3. Scatter edges into CSR slots: esrc[offs[d] + cur[d]++] = src[e].
// ---------------------------------------------------------------------------
__global__ __launch_bounds__(256) void k_scatter(
    const int* __restrict__ src, const int* __restrict__ dst,
    const int* __restrict__ offs, int* __restrict__ cur,
    int* __restrict__ esrc, int n_edges)
{
    int t = blockIdx.x * blockDim.x + threadIdx.x;
    if (t >= n_edges) return;
    int d = dst[t];
    int pos = offs[d] + atomicAdd(&cur[d], 1);
    esrc[pos] = src[t];
}

// ---------------------------------------------------------------------------
// 4. Fused gather + normalize + GEMV. One wave per node.
//    sum[lane] = sum_{e in N_in(n)} x[esrc[e]][lane]
//    h = (sum + x[n]) / (deg+1);  out[n][o] = sum_k h[k]*W[o][k] + b[o]
// ---------------------------------------------------------------------------
__global__ __launch_bounds__(256) void k_node(
    const float* __restrict__ x,
    const int* __restrict__ offs,
    const int* __restrict__ esrc,
    const float* __restrict__ W,
    const float* __restrict__ b,
    float* __restrict__ out,
    int n_nodes)
{
    __shared__ float Wt[D * D];  // Wt[k*64 + o] = W[o*64 + k]
    for (int idx = threadIdx.x; idx < D * D; idx += blockDim.x) {
        int o = idx >> 6;
        int k = idx & 63;
        Wt[k * D + o] = W[idx];
    }
    __syncthreads();

    const int wave = threadIdx.x >> 6;   // 0..3
    const int lane = threadIdx.x & 63;
    const float bias = b[lane];
    const int wavesTotal = gridDim.x * 4;

    for (int n = blockIdx.x * 4 + wave; n < n_nodes; n += wavesTotal) {
        const int e0 = offs[n];
        const int e1 = offs[n + 1];
        const int cnt = e1 - e0;

        float sum = 0.0f;
        for (int base = 0; base < cnt; base += 64) {
            int m = cnt - base; if (m > 64) m = 64;
            int sidx = (lane < m) ? esrc[e0 + base + lane] : 0;
            for (int j = 0; j < m; ++j) {
                int sj = __shfl(sidx, j, 64);
                sum += x[(size_t)sj * D + lane];
            }
        }

        const size_t row = (size_t)n * D;
        float h = (sum + x[row + lane]) / (float)(cnt + 1);

        float acc = 0.0f;
#pragma unroll
        for (int k = 0; k < D; ++k) {
            float hk = __shfl(h, k, 64);
            acc = fmaf(hk, Wt[k * D + lane], acc);
        }
        out[row + lane] = acc + bias;
    }
}

extern "C" void kernel_launch(void* const* d_in, const int* in_sizes, int n_in,
                              void* d_out, int out_size, void* d_ws, size_t ws_size,
                              hipStream_t stream)
{
    const float* x   = (const float*)d_in[0];
    const int*   src = (const int*)d_in[1];
    const int*   dst = (const int*)d_in[2];
    const float* W   = (const float*)d_in[3];
    const float* b   = (const float*)d_in[4];
    float* out = (float*)d_out;

    const int n_nodes = in_sizes[0] / D;
    const int n_edges = in_sizes[1];

    // Workspace layout (ints): [deg N][cur N][offs N+1][bsum 512][esrc E]
    int* deg  = (int*)d_ws;
    int* cur  = deg + n_nodes;
    int* offs = cur + n_nodes;
    int* bsum = offs + (n_nodes + 1);
    int* esrc = bsum + 512;

    // Zero deg + cur each call (graph-replay safe).
    hipMemsetAsync(deg, 0, (size_t)2 * n_nodes * sizeof(int), stream);

    const int nbE = (n_edges + 255) / 256;
    const int nbN = (n_nodes + SCAN_BLOCK - 1) / SCAN_BLOCK;   // 391 <= 512

    k_count<<<nbE, 256, 0, stream>>>(dst, deg, n_edges);
    k_scan1<<<nbN, SCAN_BLOCK, 0, stream>>>(deg, offs, bsum, n_nodes);
    k_scan2<<<1, 512, 0, stream>>>(bsum, offs, nbN, n_nodes);
    k_scan3<<<nbN, SCAN_BLOCK, 0, stream>>>(offs, bsum, n_nodes);
    k_scatter<<<nbE, 256, 0, stream>>>(src, dst, offs, cur, esrc, n_edges);

    const int grid = (n_nodes + 3) / 4;   // one wave per node, 4 waves/block
    k_node<<<grid, 256, 0, stream>>>(x, offs, esrc, W, b, out, n_nodes);
}

// Round 3
// 277.088 us; speedup vs baseline: 6.1550x; 1.9688x over previous
//
#include <hip/hip_runtime.h>

#define D 64
#define SCAN_BLOCK 256

// ---------------------------------------------------------------------------
// 1. Count in-degrees: deg[dst[e]]++ (int atomics).
// ---------------------------------------------------------------------------
__global__ __launch_bounds__(256) void k_count(
    const int* __restrict__ dst, int* __restrict__ deg, int n_edges)
{
    int t = blockIdx.x * blockDim.x + threadIdx.x;
    if (t < n_edges) atomicAdd(&deg[dst[t]], 1);
}

// ---------------------------------------------------------------------------
// 2a. Block-wise exclusive scan of deg -> offs; per-block totals -> bsum.
// ---------------------------------------------------------------------------
__global__ __launch_bounds__(SCAN_BLOCK) void k_scan1(
    const int* __restrict__ deg, int* __restrict__ offs,
    int* __restrict__ bsum, int n)
{
    __shared__ int s[SCAN_BLOCK];
    int tid = threadIdx.x;
    int i = blockIdx.x * SCAN_BLOCK + tid;
    int v = (i < n) ? deg[i] : 0;
    s[tid] = v;
    __syncthreads();
    for (int off = 1; off < SCAN_BLOCK; off <<= 1) {
        int t = (tid >= off) ? s[tid - off] : 0;
        __syncthreads();
        s[tid] += t;
        __syncthreads();
    }
    if (i < n) offs[i] = s[tid] - v;                 // exclusive
    if (tid == SCAN_BLOCK - 1) bsum[blockIdx.x] = s[tid];
}

// ---------------------------------------------------------------------------
// 2b. Scan the (<=512) block sums in one block; offs[n] = grand total.
// ---------------------------------------------------------------------------
__global__ __launch_bounds__(512) void k_scan2(
    int* __restrict__ bsum, int* __restrict__ offs, int nb, int n)
{
    __shared__ int s[512];
    int tid = threadIdx.x;
    int v = (tid < nb) ? bsum[tid] : 0;
    s[tid] = v;
    __syncthreads();
    for (int off = 1; off < 512; off <<= 1) {
        int t = (tid >= off) ? s[tid - off] : 0;
        __syncthreads();
        s[tid] += t;
        __syncthreads();
    }
    if (tid < nb) bsum[tid] = s[tid] - v;            // exclusive
    if (tid == 511) offs[n] = s[511];
}

// ---------------------------------------------------------------------------
// 2c. Add scanned block sums back.
// ---------------------------------------------------------------------------
__global__ __launch_bounds__(SCAN_BLOCK) void k_scan3(
    int* __restrict__ offs, const int* __restrict__ bsum, int n)
{
    int i = blockIdx.x * SCAN_BLOCK + threadIdx.x;
    if (i < n) offs[i] += bsum[blockIdx.x];
}

// ---------------------------------------------------------------------------
// 3. Scatter edges into CSR slots.
// ---------------------------------------------------------------------------
__global__ __launch_bounds__(256) void k_scatter(
    const int* __restrict__ src, const int* __restrict__ dst,
    const int* __restrict__ offs, int* __restrict__ cur,
    int* __restrict__ esrc, int n_edges)
{
    int t = blockIdx.x * blockDim.x + threadIdx.x;
    if (t >= n_edges) return;
    int d = dst[t];
    int pos = offs[d] + atomicAdd(&cur[d], 1);
    esrc[pos] = src[t];
}

// ---------------------------------------------------------------------------
// 4. Fused gather + normalize + GEMV. One wave per node (grid-stride).
//    Lanes = 4 edge-slots x 16 feature-quarters: each lane float4-gathers its
//    own edge rows (8 loads in flight, no shfl in the hot loop), reduce with
//    8 shfl_xor, normalize, stash h in a per-wave LDS row, then GEMV with
//    W[lane][:] held in 16 float4 registers (amortized across nodes).
// ---------------------------------------------------------------------------
__global__ __launch_bounds__(256, 4) void k_node(
    const float* __restrict__ x,
    const int* __restrict__ offs,
    const int* __restrict__ esrc,
    const float* __restrict__ W,
    const float* __restrict__ b,
    float* __restrict__ out,
    int n_nodes)
{
    __shared__ __align__(16) float hbuf[4][D];

    const int wave = threadIdx.x >> 6;
    const int lane = threadIdx.x & 63;
    const int grp  = lane >> 4;        // edge slot 0..3
    const int fq   = lane & 15;        // feature quarter 0..15

    const float4* __restrict__ x4 = (const float4*)x;
    const float4* __restrict__ W4 = (const float4*)W;

    // Lane owns output feature o = lane: preload W[lane][0..63].
    float4 w[16];
#pragma unroll
    for (int j = 0; j < 16; ++j) w[j] = W4[lane * 16 + j];
    const float bias = b[lane];

    const int wavesTotal = gridDim.x * 4;
    for (int n = blockIdx.x * 4 + wave; n < n_nodes; n += wavesTotal) {
        const int e0  = offs[n];
        const int cnt = offs[n + 1] - e0;

        float4 s = make_float4(0.f, 0.f, 0.f, 0.f);
        if (cnt > 0) {
            for (int base = 0; base < cnt; base += 8) {
                int i0 = base + grp;
                int i1 = base + 4 + grp;
                float m0 = (i0 < cnt) ? 1.0f : 0.0f;
                float m1 = (i1 < cnt) ? 1.0f : 0.0f;
                int c0 = min(i0, cnt - 1);
                int c1 = min(i1, cnt - 1);
                int s0 = esrc[e0 + c0];
                int s1 = esrc[e0 + c1];
                float4 v0 = x4[(size_t)s0 * 16 + fq];
                float4 v1 = x4[(size_t)s1 * 16 + fq];
                s.x = fmaf(m0, v0.x, s.x);
                s.y = fmaf(m0, v0.y, s.y);
                s.z = fmaf(m0, v0.z, s.z);
                s.w = fmaf(m0, v0.w, s.w);
                s.x = fmaf(m1, v1.x, s.x);
                s.y = fmaf(m1, v1.y, s.y);
                s.z = fmaf(m1, v1.z, s.z);
                s.w = fmaf(m1, v1.w, s.w);
            }
        }
        // Reduce the 4 edge slots (flip grp bits: lane^16, lane^32).
        s.x += __shfl_xor(s.x, 16, 64);
        s.y += __shfl_xor(s.y, 16, 64);
        s.z += __shfl_xor(s.z, 16, 64);
        s.w += __shfl_xor(s.w, 16, 64);
        s.x += __shfl_xor(s.x, 32, 64);
        s.y += __shfl_xor(s.y, 32, 64);
        s.z += __shfl_xor(s.z, 32, 64);
        s.w += __shfl_xor(s.w, 32, 64);

        // Self term + normalize; group 0 writes h row to LDS (wave-local).
        if (grp == 0) {
            float4 xv = x4[(size_t)n * 16 + fq];
            float rinv = 1.0f / (float)(cnt + 1);
            float4 h;
            h.x = (s.x + xv.x) * rinv;
            h.y = (s.y + xv.y) * rinv;
            h.z = (s.z + xv.z) * rinv;
            h.w = (s.w + xv.w) * rinv;
            *(float4*)&hbuf[wave][fq * 4] = h;
        }

        // GEMV: 16 broadcast b128 LDS reads + 64 FMAs.
        float acc = bias;
#pragma unroll
        for (int j = 0; j < 16; ++j) {
            float4 hk = *(const float4*)&hbuf[wave][j * 4];
            acc = fmaf(hk.x, w[j].x, acc);
            acc = fmaf(hk.y, w[j].y, acc);
            acc = fmaf(hk.z, w[j].z, acc);
            acc = fmaf(hk.w, w[j].w, acc);
        }
        out[(size_t)n * D + lane] = acc;
    }
}

extern "C" void kernel_launch(void* const* d_in, const int* in_sizes, int n_in,
                              void* d_out, int out_size, void* d_ws, size_t ws_size,
                              hipStream_t stream)
{
    const float* x   = (const float*)d_in[0];
    const int*   src = (const int*)d_in[1];
    const int*   dst = (const int*)d_in[2];
    const float* W   = (const float*)d_in[3];
    const float* b   = (const float*)d_in[4];
    float* out = (float*)d_out;

    const int n_nodes = in_sizes[0] / D;
    const int n_edges = in_sizes[1];

    // Workspace (ints): [deg N][cur N][offs N+1][bsum 512][esrc E]
    int* deg  = (int*)d_ws;
    int* cur  = deg + n_nodes;
    int* offs = cur + n_nodes;
    int* bsum = offs + (n_nodes + 1);
    int* esrc = bsum + 512;

    hipMemsetAsync(deg, 0, (size_t)2 * n_nodes * sizeof(int), stream);

    const int nbE = (n_edges + 255) / 256;
    const int nbN = (n_nodes + SCAN_BLOCK - 1) / SCAN_BLOCK;   // 391 <= 512

    k_count<<<nbE, 256, 0, stream>>>(dst, deg, n_edges);
    k_scan1<<<nbN, SCAN_BLOCK, 0, stream>>>(deg, offs, bsum, n_nodes);
    k_scan2<<<1, 512, 0, stream>>>(bsum, offs, nbN, n_nodes);
    k_scan3<<<nbN, SCAN_BLOCK, 0, stream>>>(offs, bsum, n_nodes);
    k_scatter<<<nbE, 256, 0, stream>>>(src, dst, offs, cur, esrc, n_edges);

    // Grid-stride: 2048 blocks x 4 waves -> each wave handles ~12 nodes,
    // amortizing the per-wave W preload.
    k_node<<<2048, 256, 0, stream>>>(x, offs, esrc, W, b, out, n_nodes);
}

// Round 4
// 140.549 us; speedup vs baseline: 12.1344x; 1.9715x over previous
//
#include <hip/hip_runtime.h>

#define D 64
#define NBMAX 512        // max buckets supported (nodes <= 131072)
#define TILE 4096        // edges per block in bucket passes

// ---------------------------------------------------------------------------
// A1. Per-block bucket histogram (bucket = dst>>8, 256 nodes each); reserve
//     per-block ranges via one global atomicAdd per bucket per block.
// ---------------------------------------------------------------------------
__global__ __launch_bounds__(256) void k_bhist(
    const int* __restrict__ dst, int* __restrict__ bucketCount,
    int* __restrict__ blockBase, int nb, int n_edges)
{
    __shared__ int hist[NBMAX];
    const int tid = threadIdx.x;
    for (int i = tid; i < nb; i += 256) hist[i] = 0;
    __syncthreads();

    const int e0 = blockIdx.x * TILE;
    const int n4 = n_edges >> 2;
    const int4* dst4 = (const int4*)dst;
#pragma unroll
    for (int k = 0; k < 4; ++k) {
        int i4 = (e0 >> 2) + k * 256 + tid;
        if (i4 < n4) {
            int4 d = dst4[i4];
            atomicAdd(&hist[d.x >> 8], 1);
            atomicAdd(&hist[d.y >> 8], 1);
            atomicAdd(&hist[d.z >> 8], 1);
            atomicAdd(&hist[d.w >> 8], 1);
        }
    }
    if (blockIdx.x == gridDim.x - 1) {           // scalar tail (E % 4 != 0)
        for (int e = (n4 << 2) + tid; e < n_edges; e += 256)
            atomicAdd(&hist[dst[e] >> 8], 1);
    }
    __syncthreads();
    for (int i = tid; i < nb; i += 256)
        blockBase[(size_t)blockIdx.x * nb + i] = atomicAdd(&bucketCount[i], hist[i]);
}

// ---------------------------------------------------------------------------
// A2. Scan bucket counts -> bucket bases; also offs[N] = E.
// ---------------------------------------------------------------------------
__global__ __launch_bounds__(512) void k_bscan(
    const int* __restrict__ bucketCount, int* __restrict__ bucketBase,
    int* __restrict__ offs, int nb, int n_nodes, int n_edges)
{
    __shared__ int s[512];
    const int tid = threadIdx.x;
    int v = (tid < nb) ? bucketCount[tid] : 0;
    s[tid] = v;
    __syncthreads();
    for (int off = 1; off < 512; off <<= 1) {
        int t = (tid >= off) ? s[tid - off] : 0;
        __syncthreads();
        s[tid] += t;
        __syncthreads();
    }
    if (tid <= nb) bucketBase[tid] = s[tid] - v;   // exclusive (v=0 for tid>=nb)
    if (tid == 0) offs[n_nodes] = n_edges;
}

// ---------------------------------------------------------------------------
// A3. Scatter (src,dst) pairs into bucket-grouped runs. LDS cursors start at
//     bucketBase + this block's reserved offset -> contiguous ~84B runs.
// ---------------------------------------------------------------------------
__global__ __launch_bounds__(256) void k_bscatter(
    const int* __restrict__ src, const int* __restrict__ dst,
    const int* __restrict__ bucketBase, const int* __restrict__ blockBase,
    int2* __restrict__ pairs, int nb, int n_edges)
{
    __shared__ int cur[NBMAX];
    const int tid = threadIdx.x;
    const int blk = blockIdx.x;
    for (int i = tid; i < nb; i += 256)
        cur[i] = bucketBase[i] + blockBase[(size_t)blk * nb + i];
    __syncthreads();

    const int e0 = blk * TILE;
    const int n4 = n_edges >> 2;
    const int4* src4 = (const int4*)src;
    const int4* dst4 = (const int4*)dst;
#pragma unroll
    for (int k = 0; k < 4; ++k) {
        int i4 = (e0 >> 2) + k * 256 + tid;
        if (i4 < n4) {
            int4 sv = src4[i4];
            int4 dv = dst4[i4];
            int p;
            p = atomicAdd(&cur[dv.x >> 8], 1); pairs[p] = make_int2(sv.x, dv.x);
            p = atomicAdd(&cur[dv.y >> 8], 1); pairs[p] = make_int2(sv.y, dv.y);
            p = atomicAdd(&cur[dv.z >> 8], 1); pairs[p] = make_int2(sv.z, dv.z);
            p = atomicAdd(&cur[dv.w >> 8], 1); pairs[p] = make_int2(sv.w, dv.w);
        }
    }
    if (blk == gridDim.x - 1) {
        for (int e = (n4 << 2) + tid; e < n_edges; e += 256) {
            int p = atomicAdd(&cur[dst[e] >> 8], 1);
            pairs[p] = make_int2(src[e], dst[e]);
        }
    }
}

// ---------------------------------------------------------------------------
// B. Per-bucket CSR finalize: LDS degree histogram over the bucket's 256
//    nodes, LDS scan -> offs (coalesced), then cache-local esrc scatter.
// ---------------------------------------------------------------------------
__global__ __launch_bounds__(256) void k_csr(
    const int2* __restrict__ pairs, const int* __restrict__ bucketBase,
    int* __restrict__ offs, int* __restrict__ esrc, int n_nodes)
{
    __shared__ int ldeg[256];
    __shared__ int lofs[256];
    const int tid = threadIdx.x;
    const int node0 = blockIdx.x << 8;
    const int ebase = bucketBase[blockIdx.x];
    const int ecnt  = bucketBase[blockIdx.x + 1] - ebase;

    ldeg[tid] = 0;
    __syncthreads();
    for (int i = tid; i < ecnt; i += 256)
        atomicAdd(&ldeg[pairs[ebase + i].y - node0], 1);
    __syncthreads();

    int v = ldeg[tid];
    lofs[tid] = v;
    __syncthreads();
    for (int off = 1; off < 256; off <<= 1) {
        int t = (tid >= off) ? lofs[tid - off] : 0;
        __syncthreads();
        lofs[tid] += t;
        __syncthreads();
    }
    const int my = lofs[tid] - v;                 // exclusive
    if (node0 + tid < n_nodes) offs[node0 + tid] = ebase + my;

    ldeg[tid] = ebase + my;                       // cursors
    __syncthreads();
    for (int i = tid; i < ecnt; i += 256) {
        int2 p = pairs[ebase + i];
        int pos = atomicAdd(&ldeg[p.y - node0], 1);
        esrc[pos] = p.x;
    }
}

// ---------------------------------------------------------------------------
// C. Fused gather + normalize + GEMV (unchanged from round 3).
// ---------------------------------------------------------------------------
__global__ __launch_bounds__(256, 4) void k_node(
    const float* __restrict__ x,
    const int* __restrict__ offs,
    const int* __restrict__ esrc,
    const float* __restrict__ W,
    const float* __restrict__ b,
    float* __restrict__ out,
    int n_nodes)
{
    __shared__ __align__(16) float hbuf[4][D];

    const int wave = threadIdx.x >> 6;
    const int lane = threadIdx.x & 63;
    const int grp  = lane >> 4;
    const int fq   = lane & 15;

    const float4* __restrict__ x4 = (const float4*)x;
    const float4* __restrict__ W4 = (const float4*)W;

    float4 w[16];
#pragma unroll
    for (int j = 0; j < 16; ++j) w[j] = W4[lane * 16 + j];
    const float bias = b[lane];

    const int wavesTotal = gridDim.x * 4;
    for (int n = blockIdx.x * 4 + wave; n < n_nodes; n += wavesTotal) {
        const int e0  = offs[n];
        const int cnt = offs[n + 1] - e0;

        float4 s = make_float4(0.f, 0.f, 0.f, 0.f);
        if (cnt > 0) {
            for (int base = 0; base < cnt; base += 8) {
                int i0 = base + grp;
                int i1 = base + 4 + grp;
                float m0 = (i0 < cnt) ? 1.0f : 0.0f;
                float m1 = (i1 < cnt) ? 1.0f : 0.0f;
                int c0 = min(i0, cnt - 1);
                int c1 = min(i1, cnt - 1);
                int s0 = esrc[e0 + c0];
                int s1 = esrc[e0 + c1];
                float4 v0 = x4[(size_t)s0 * 16 + fq];
                float4 v1 = x4[(size_t)s1 * 16 + fq];
                s.x = fmaf(m0, v0.x, s.x);
                s.y = fmaf(m0, v0.y, s.y);
                s.z = fmaf(m0, v0.z, s.z);
                s.w = fmaf(m0, v0.w, s.w);
                s.x = fmaf(m1, v1.x, s.x);
                s.y = fmaf(m1, v1.y, s.y);
                s.z = fmaf(m1, v1.z, s.z);
                s.w = fmaf(m1, v1.w, s.w);
            }
        }
        s.x += __shfl_xor(s.x, 16, 64);
        s.y += __shfl_xor(s.y, 16, 64);
        s.z += __shfl_xor(s.z, 16, 64);
        s.w += __shfl_xor(s.w, 16, 64);
        s.x += __shfl_xor(s.x, 32, 64);
        s.y += __shfl_xor(s.y, 32, 64);
        s.z += __shfl_xor(s.z, 32, 64);
        s.w += __shfl_xor(s.w, 32, 64);

        if (grp == 0) {
            float4 xv = x4[(size_t)n * 16 + fq];
            float rinv = 1.0f / (float)(cnt + 1);
            float4 h;
            h.x = (s.x + xv.x) * rinv;
            h.y = (s.y + xv.y) * rinv;
            h.z = (s.z + xv.z) * rinv;
            h.w = (s.w + xv.w) * rinv;
            *(float4*)&hbuf[wave][fq * 4] = h;
        }

        float acc = bias;
#pragma unroll
        for (int j = 0; j < 16; ++j) {
            float4 hk = *(const float4*)&hbuf[wave][j * 4];
            acc = fmaf(hk.x, w[j].x, acc);
            acc = fmaf(hk.y, w[j].y, acc);
            acc = fmaf(hk.z, w[j].z, acc);
            acc = fmaf(hk.w, w[j].w, acc);
        }
        out[(size_t)n * D + lane] = acc;
    }
}

extern "C" void kernel_launch(void* const* d_in, const int* in_sizes, int n_in,
                              void* d_out, int out_size, void* d_ws, size_t ws_size,
                              hipStream_t stream)
{
    const float* x   = (const float*)d_in[0];
    const int*   src = (const int*)d_in[1];
    const int*   dst = (const int*)d_in[2];
    const float* W   = (const float*)d_in[3];
    const float* b   = (const float*)d_in[4];
    float* out = (float*)d_out;

    const int n_nodes = in_sizes[0] / D;
    const int n_edges = in_sizes[1];
    const int nb  = (n_nodes + 255) >> 8;               // buckets (<= NBMAX)
    const int nbA = (n_edges + TILE - 1) / TILE;        // edge-pass blocks

    // Workspace (pairs first for 8B alignment):
    // [pairs 2E][bucketCount NBMAX][bucketBase NBMAX+1][offs N+1]
    // [blockBase nbA*nb][esrc E]
    int2* pairs      = (int2*)d_ws;
    int*  bucketCount= (int*)(pairs + n_edges);
    int*  bucketBase = bucketCount + NBMAX;
    int*  offs       = bucketBase + NBMAX + 1;
    int*  blockBase  = offs + (n_nodes + 1);
    int*  esrc       = blockBase + (size_t)nbA * nb;

    hipMemsetAsync(bucketCount, 0, NBMAX * sizeof(int), stream);

    k_bhist   <<<nbA, 256, 0, stream>>>(dst, bucketCount, blockBase, nb, n_edges);
    k_bscan   <<<1,   512, 0, stream>>>(bucketCount, bucketBase, offs, nb, n_nodes, n_edges);
    k_bscatter<<<nbA, 256, 0, stream>>>(src, dst, bucketBase, blockBase, pairs, nb, n_edges);
    k_csr     <<<nb,  256, 0, stream>>>(pairs, bucketBase, offs, esrc, n_nodes);
    k_node    <<<2048,256, 0, stream>>>(x, offs, esrc, W, b, out, n_nodes);
}

// Round 5
// 133.661 us; speedup vs baseline: 12.7597x; 1.0515x over previous
//
#include <hip/hip_runtime.h>

#define D 64
#define NBMAX 512        // max buckets (nodes <= 131072)
#define TILE 4096        // edges per block in bucket passes

typedef unsigned int  uint;
typedef unsigned short ushort_t;

// ---------------------------------------------------------------------------
// 0. x (fp32) -> bf16 (RNE), packed 8 elems/thread.
// ---------------------------------------------------------------------------
__global__ __launch_bounds__(256) void k_tobf16(
    const float4* __restrict__ x4, uint4* __restrict__ xb4, int n8)
{
    int t = blockIdx.x * blockDim.x + threadIdx.x;
    if (t >= n8) return;
    float4 a = x4[t * 2];
    float4 c = x4[t * 2 + 1];
    float vals[8] = {a.x, a.y, a.z, a.w, c.x, c.y, c.z, c.w};
    ushort_t r[8];
#pragma unroll
    for (int i = 0; i < 8; ++i) {
        uint u = __float_as_uint(vals[i]);
        u += 0x7FFFu + ((u >> 16) & 1u);          // round-to-nearest-even
        r[i] = (ushort_t)(u >> 16);
    }
    uint4 o;
    o.x = (uint)r[0] | ((uint)r[1] << 16);
    o.y = (uint)r[2] | ((uint)r[3] << 16);
    o.z = (uint)r[4] | ((uint)r[5] << 16);
    o.w = (uint)r[6] | ((uint)r[7] << 16);
    xb4[t] = o;
}

// ---------------------------------------------------------------------------
// A1. Per-block bucket histogram (bucket = dst>>8); reserve per-block ranges.
// ---------------------------------------------------------------------------
__global__ __launch_bounds__(256) void k_bhist(
    const int* __restrict__ dst, int* __restrict__ bucketCount,
    int* __restrict__ blockBase, int nb, int n_edges)
{
    __shared__ int hist[NBMAX];
    const int tid = threadIdx.x;
    for (int i = tid; i < nb; i += 256) hist[i] = 0;
    __syncthreads();

    const int e0 = blockIdx.x * TILE;
    const int n4 = n_edges >> 2;
    const int4* dst4 = (const int4*)dst;
#pragma unroll
    for (int k = 0; k < 4; ++k) {
        int i4 = (e0 >> 2) + k * 256 + tid;
        if (i4 < n4) {
            int4 d = dst4[i4];
            atomicAdd(&hist[d.x >> 8], 1);
            atomicAdd(&hist[d.y >> 8], 1);
            atomicAdd(&hist[d.z >> 8], 1);
            atomicAdd(&hist[d.w >> 8], 1);
        }
    }
    if (blockIdx.x == gridDim.x - 1) {
        for (int e = (n4 << 2) + tid; e < n_edges; e += 256)
            atomicAdd(&hist[dst[e] >> 8], 1);
    }
    __syncthreads();
    for (int i = tid; i < nb; i += 256)
        blockBase[(size_t)blockIdx.x * nb + i] = atomicAdd(&bucketCount[i], hist[i]);
}

// ---------------------------------------------------------------------------
// A2. Scan bucket counts -> bucket bases; offs[N] = E.
// ---------------------------------------------------------------------------
__global__ __launch_bounds__(512) void k_bscan(
    const int* __restrict__ bucketCount, int* __restrict__ bucketBase,
    int* __restrict__ offs, int nb, int n_nodes, int n_edges)
{
    __shared__ int s[512];
    const int tid = threadIdx.x;
    int v = (tid < nb) ? bucketCount[tid] : 0;
    s[tid] = v;
    __syncthreads();
    for (int off = 1; off < 512; off <<= 1) {
        int t = (tid >= off) ? s[tid - off] : 0;
        __syncthreads();
        s[tid] += t;
        __syncthreads();
    }
    if (tid <= nb) bucketBase[tid] = s[tid] - v;
    if (tid == 0) offs[n_nodes] = n_edges;
}

// ---------------------------------------------------------------------------
// A3. Scatter packed (src | dst_low8<<24) into bucket-grouped runs.
// ---------------------------------------------------------------------------
__global__ __launch_bounds__(256) void k_bscatter(
    const int* __restrict__ src, const int* __restrict__ dst,
    const int* __restrict__ bucketBase, const int* __restrict__ blockBase,
    int* __restrict__ packed, int nb, int n_edges)
{
    __shared__ int cur[NBMAX];
    const int tid = threadIdx.x;
    const int blk = blockIdx.x;
    for (int i = tid; i < nb; i += 256)
        cur[i] = bucketBase[i] + blockBase[(size_t)blk * nb + i];
    __syncthreads();

    const int e0 = blk * TILE;
    const int n4 = n_edges >> 2;
    const int4* src4 = (const int4*)src;
    const int4* dst4 = (const int4*)dst;
#pragma unroll
    for (int k = 0; k < 4; ++k) {
        int i4 = (e0 >> 2) + k * 256 + tid;
        if (i4 < n4) {
            int4 sv = src4[i4];
            int4 dv = dst4[i4];
            int p;
            p = atomicAdd(&cur[dv.x >> 8], 1); packed[p] = sv.x | ((dv.x & 255) << 24);
            p = atomicAdd(&cur[dv.y >> 8], 1); packed[p] = sv.y | ((dv.y & 255) << 24);
            p = atomicAdd(&cur[dv.z >> 8], 1); packed[p] = sv.z | ((dv.z & 255) << 24);
            p = atomicAdd(&cur[dv.w >> 8], 1); packed[p] = sv.w | ((dv.w & 255) << 24);
        }
    }
    if (blk == gridDim.x - 1) {
        for (int e = (n4 << 2) + tid; e < n_edges; e += 256) {
            int p = atomicAdd(&cur[dst[e] >> 8], 1);
            packed[p] = src[e] | ((dst[e] & 255) << 24);
        }
    }
}

// ---------------------------------------------------------------------------
// B. Per-bucket CSR finalize (LDS histogram + scan + cache-local scatter).
// ---------------------------------------------------------------------------
__global__ __launch_bounds__(256) void k_csr(
    const int* __restrict__ packed, const int* __restrict__ bucketBase,
    int* __restrict__ offs, int* __restrict__ esrc, int n_nodes)
{
    __shared__ int ldeg[256];
    __shared__ int lofs[256];
    const int tid = threadIdx.x;
    const int node0 = blockIdx.x << 8;
    const int ebase = bucketBase[blockIdx.x];
    const int ecnt  = bucketBase[blockIdx.x + 1] - ebase;

    ldeg[tid] = 0;
    __syncthreads();
    for (int i = tid; i < ecnt; i += 256)
        atomicAdd(&ldeg[((uint)packed[ebase + i]) >> 24], 1);
    __syncthreads();

    int v = ldeg[tid];
    lofs[tid] = v;
    __syncthreads();
    for (int off = 1; off < 256; off <<= 1) {
        int t = (tid >= off) ? lofs[tid - off] : 0;
        __syncthreads();
        lofs[tid] += t;
        __syncthreads();
    }
    const int my = lofs[tid] - v;
    if (node0 + tid < n_nodes) offs[node0 + tid] = ebase + my;

    ldeg[tid] = ebase + my;
    __syncthreads();
    for (int i = tid; i < ecnt; i += 256) {
        int pk = packed[ebase + i];
        int pos = atomicAdd(&ldeg[((uint)pk) >> 24], 1);
        esrc[pos] = pk & 0x00FFFFFF;
    }
}

// ---------------------------------------------------------------------------
// C. Fused gather(bf16) + normalize + GEMV. One wave per node (grid-stride).
//    Lanes = 8 edge-slots x 8 feature-eighths; each lane loads 16B = 8 bf16
//    feats of its slot's edge row; unroll 2 -> 16 edges in flight per wave.
// ---------------------------------------------------------------------------
__global__ __launch_bounds__(256, 4) void k_node(
    const float* __restrict__ x,
    const uint4* __restrict__ xb4,     // bf16 rows: 8 uint4 per node
    const int* __restrict__ offs,
    const int* __restrict__ esrc,
    const float* __restrict__ W,
    const float* __restrict__ b,
    float* __restrict__ out,
    int n_nodes)
{
    __shared__ __align__(16) float hbuf[4][D];

    const int wave = threadIdx.x >> 6;
    const int lane = threadIdx.x & 63;
    const int slot = lane >> 3;        // edge slot 0..7
    const int f8   = lane & 7;         // feature-eighth: feats f8*8 .. f8*8+7

    const float4* __restrict__ x4 = (const float4*)x;
    const float4* __restrict__ W4 = (const float4*)W;

    float4 w[16];
#pragma unroll
    for (int j = 0; j < 16; ++j) w[j] = W4[lane * 16 + j];
    const float bias = b[lane];

#define CVLO(u) __uint_as_float((u) << 16)
#define CVHI(u) __uint_as_float((u) & 0xFFFF0000u)

    const int wavesTotal = gridDim.x * 4;
    for (int n = blockIdx.x * 4 + wave; n < n_nodes; n += wavesTotal) {
        const int e0  = offs[n];
        const int cnt = offs[n + 1] - e0;

        float s[8];
#pragma unroll
        for (int i = 0; i < 8; ++i) s[i] = 0.0f;

        for (int base = 0; base < cnt; base += 16) {
            int i0 = base + slot;
            int i1 = base + 8 + slot;
            float m0 = (i0 < cnt) ? 1.0f : 0.0f;
            float m1 = (i1 < cnt) ? 1.0f : 0.0f;
            int c0 = min(i0, cnt - 1);
            int c1 = min(i1, cnt - 1);
            int s0 = esrc[e0 + c0];
            int s1 = esrc[e0 + c1];
            uint4 v0 = xb4[(size_t)s0 * 8 + f8];
            uint4 v1 = xb4[(size_t)s1 * 8 + f8];
            s[0] = fmaf(m0, CVLO(v0.x), s[0]);
            s[1] = fmaf(m0, CVHI(v0.x), s[1]);
            s[2] = fmaf(m0, CVLO(v0.y), s[2]);
            s[3] = fmaf(m0, CVHI(v0.y), s[3]);
            s[4] = fmaf(m0, CVLO(v0.z), s[4]);
            s[5] = fmaf(m0, CVHI(v0.z), s[5]);
            s[6] = fmaf(m0, CVLO(v0.w), s[6]);
            s[7] = fmaf(m0, CVHI(v0.w), s[7]);
            s[0] = fmaf(m1, CVLO(v1.x), s[0]);
            s[1] = fmaf(m1, CVHI(v1.x), s[1]);
            s[2] = fmaf(m1, CVLO(v1.y), s[2]);
            s[3] = fmaf(m1, CVHI(v1.y), s[3]);
            s[4] = fmaf(m1, CVLO(v1.z), s[4]);
            s[5] = fmaf(m1, CVHI(v1.z), s[5]);
            s[6] = fmaf(m1, CVLO(v1.w), s[6]);
            s[7] = fmaf(m1, CVHI(v1.w), s[7]);
        }

        // Reduce across the 8 slots (lanes differing in bits 3..5).
#pragma unroll
        for (int i = 0; i < 8; ++i) {
            s[i] += __shfl_xor(s[i], 8, 64);
            s[i] += __shfl_xor(s[i], 16, 64);
            s[i] += __shfl_xor(s[i], 32, 64);
        }

        // Slot-0 lanes: self term (fp32), normalize, publish h.
        if (slot == 0) {
            float4 xa = x4[(size_t)n * 16 + f8 * 2];
            float4 xc = x4[(size_t)n * 16 + f8 * 2 + 1];
            float rinv = 1.0f / (float)(cnt + 1);
            float4 h0, h1;
            h0.x = (s[0] + xa.x) * rinv;
            h0.y = (s[1] + xa.y) * rinv;
            h0.z = (s[2] + xa.z) * rinv;
            h0.w = (s[3] + xa.w) * rinv;
            h1.x = (s[4] + xc.x) * rinv;
            h1.y = (s[5] + xc.y) * rinv;
            h1.z = (s[6] + xc.z) * rinv;
            h1.w = (s[7] + xc.w) * rinv;
            *(float4*)&hbuf[wave][f8 * 8]     = h0;
            *(float4*)&hbuf[wave][f8 * 8 + 4] = h1;
        }

        // GEMV: lane owns output feature `lane`.
        float acc = bias;
#pragma unroll
        for (int j = 0; j < 16; ++j) {
            float4 hk = *(const float4*)&hbuf[wave][j * 4];
            acc = fmaf(hk.x, w[j].x, acc);
            acc = fmaf(hk.y, w[j].y, acc);
            acc = fmaf(hk.z, w[j].z, acc);
            acc = fmaf(hk.w, w[j].w, acc);
        }
        out[(size_t)n * D + lane] = acc;
    }
#undef CVLO
#undef CVHI
}

extern "C" void kernel_launch(void* const* d_in, const int* in_sizes, int n_in,
                              void* d_out, int out_size, void* d_ws, size_t ws_size,
                              hipStream_t stream)
{
    const float* x   = (const float*)d_in[0];
    const int*   src = (const int*)d_in[1];
    const int*   dst = (const int*)d_in[2];
    const float* W   = (const float*)d_in[3];
    const float* b   = (const float*)d_in[4];
    float* out = (float*)d_out;

    const int n_nodes = in_sizes[0] / D;
    const int n_edges = in_sizes[1];
    const int nb  = (n_nodes + 255) >> 8;
    const int nbA = (n_edges + TILE - 1) / TILE;

    // Workspace: [xb N*64 bf16][bucketCount NBMAX][bucketBase NBMAX+1]
    //            [offs N+1][blockBase nbA*nb][packed E][esrc E]
    ushort_t* xb  = (ushort_t*)d_ws;
    int* bucketCount = (int*)(xb + (size_t)n_nodes * D);
    int* bucketBase  = bucketCount + NBMAX;
    int* offs        = bucketBase + NBMAX + 1;
    int* blockBase   = offs + (n_nodes + 1);
    int* packed      = blockBase + (size_t)nbA * nb;
    int* esrc        = packed + n_edges;

    hipMemsetAsync(bucketCount, 0, NBMAX * sizeof(int), stream);

    const int n8 = n_nodes * D / 8;
    k_tobf16  <<<(n8 + 255) / 256, 256, 0, stream>>>((const float4*)x, (uint4*)xb, n8);
    k_bhist   <<<nbA, 256, 0, stream>>>(dst, bucketCount, blockBase, nb, n_edges);
    k_bscan   <<<1,   512, 0, stream>>>(bucketCount, bucketBase, offs, nb, n_nodes, n_edges);
    k_bscatter<<<nbA, 256, 0, stream>>>(src, dst, bucketBase, blockBase, packed, nb, n_edges);
    k_csr     <<<nb,  256, 0, stream>>>(packed, bucketBase, offs, esrc, n_nodes);
    k_node    <<<2048,256, 0, stream>>>(x, (const uint4*)xb, offs, esrc, W, b, out, n_nodes);
}